// Round 12
// baseline (261.495 us; speedup 1.0000x reference)
//
#include <hip/hip_runtime.h>
#include <math.h>

#define NPTS 262144
#define PTS  32
#define NBLK (NPTS / PTS)   // 8192 blocks, 64 threads (ONE wave), 32 points each

typedef _Float16 f16;
typedef f16    f16x4 __attribute__((ext_vector_type(4)));
typedef f16    f16x8 __attribute__((ext_vector_type(8)));
typedef __fp16 h16x2 __attribute__((ext_vector_type(2)));
typedef __fp16 h16x4 __attribute__((ext_vector_type(4)));
typedef float  f32x4 __attribute__((ext_vector_type(4)));
typedef float  f32x16 __attribute__((ext_vector_type(16)));
typedef int    i32x4 __attribute__((ext_vector_type(4)));

// R26: 32-POINT single-wave blocks using mfma_f32_32x32x16_f16.
//   R25 post-mortem: 1.5x streams (occupancy 22->31.6%) -> time FLAT ->
//   streams model falsified. Cross-round facts: time invariant to wave count
//   (1/2/3 per SIMD), +-30% instr, pipelining, code size; no pipe >35%.
//   Untested corner: MFMA shape. 16x16x32 pays 64 lanes for 16 points.
//   32x32x16: B = 32 pts (col=lane&31, every lane distinct work) ->
//   per-point A-loads/addressing/staging/epilogue HALVED, MFMA pipe -18%,
//   DS bytes/pt and transform VALU/pt unchanged. LDS 40960 B -> 4 blocks/CU
//   -> 128 pts in flight (same as champion). If this is also flat, the
//   plateau is structural and R23 is the floor.
// Layouts (32x32x16, verified D from m74/m101; A/B by the same col=lane&31):
//   A: lane holds W[n0 + (lane&31)][k = (lane>>5)*8 + j]
//   B: lane holds act[pt = lane&31][k = (lane>>5)*8 + j]
//   D: col(pt) = lane&31, row(neuron) = (reg&3) + 8*(reg>>2) + 4*(lane>>5)
//     -> reg-group rg holds 4 CONSECUTIVE neurons n0+rg*8+4*hi (b64 writes).
//   Lanes l and l+32 share pt, hold complementary neuron halves; exchange
//   via wave-private in-order LDS (no barriers, as before).
// LDS: 5 ch x 32 pt x 256B = 40960 B; swizzle byte ^= (pt&15)<<4 ->
//   uniform bank coverage (conflict-free wave64 minimum) for reads+writes.

__device__ __forceinline__ h16x2 pk(float a, float b) {
    return __builtin_amdgcn_cvt_pkrtz(a, b);          // v_cvt_pkrtz_f16_f32
}
__device__ __forceinline__ f16x4 mrg(h16x2 lo, h16x2 hi) {
    h16x4 v = __builtin_shufflevector(lo, hi, 0, 1, 2, 3);
    return __builtin_bit_cast(f16x4, v);
}
__device__ __forceinline__ int bc(h16x2 v) {
    return __builtin_bit_cast(int, v);
}
__device__ __forceinline__ f32x16 zero16() {
    f32x16 z;
#pragma unroll
    for (int i = 0; i < 16; ++i) z[i] = 0.f;
    return z;
}

__device__ __forceinline__ float fast_tanh(float z) {
    float e = __expf(2.f * z);                  // inf for large z -> t=1; 0 for very neg -> t=-1
    float r = __builtin_amdgcn_rcpf(e + 1.f);
    return __builtin_fmaf(-2.f, r, 1.f);
}

__global__ void prep_weights(const float* __restrict__ W1, const float* __restrict__ W2,
                             const float* __restrict__ W3, const float* __restrict__ Wo,
                             const float* __restrict__ bo,
                             f16* __restrict__ wt1, f16* __restrict__ wt2,
                             f16* __restrict__ wt3, f16* __restrict__ wot,
                             float* __restrict__ bot)
{
    int tid    = blockIdx.x * blockDim.x + threadIdx.x;
    int stride = gridDim.x * blockDim.x;
    for (int i = tid; i < 128 * 16; i += stride) {      // wt1: [n][16], K=16 (12 real)
        int k = i & 15, n = i >> 4;
        wt1[n * 16 + k] = (f16)((k < 12) ? W1[k * 128 + n] : 0.f);
    }
    for (int i = tid; i < 128 * 128; i += stride) {     // wt2/wt3: [n][128]
        int k = i >> 7, n = i & 127;
        wt2[n * 128 + k] = (f16)W2[i];
        wt3[n * 128 + k] = (f16)W3[i];
    }
    for (int i = tid; i < 32 * 128; i += stride) {      // wot: [n<32][128], 7 real
        int k = i >> 5, n = i & 31;
        wot[n * 128 + k] = (f16)((n < 7) ? Wo[k * 7 + n] : 0.f);
    }
    if (tid < 32) bot[tid] = (tid < 7) ? bo[tid] : 0.f;
}

// Writes neurons n..n+3 of point pt, all 5 channels. Channel stride 8192 B.
// Swizzled: element e of row (c,pt) at byte c*8192 + pt*256 + ((2e)^key),
// key = (pt&15)<<4. (n multiple of 4 -> 8B-aligned b64 writes.)
__device__ __forceinline__ void transform_store4(
    char* sA, const f32x4 a0v, const f32x4 a1v, const f32x4 a2v,
    const f32x4 a3v, const f32x4 a4v, int pt, int n)
{
    float t[4], s[4];
#pragma unroll
    for (int r = 0; r < 4; ++r) {
        t[r] = fast_tanh(a0v[r]);
        s[r] = 1.f - t[r] * t[r];
    }
    h16x2 T[2]  = { pk(t[0], t[1]), pk(t[2], t[3]) };
    h16x2 S[2]  = { pk(s[0], s[1]), pk(s[2], s[3]) };
    h16x2 A1[2] = { pk(a1v[0], a1v[1]), pk(a1v[2], a1v[3]) };
    h16x2 A2[2] = { pk(a2v[0], a2v[1]), pk(a2v[2], a2v[3]) };
    h16x2 A3[2] = { pk(a3v[0], a3v[1]), pk(a3v[2], a3v[3]) };
    h16x2 A4[2] = { pk(a4v[0], a4v[1]), pk(a4v[2], a4v[3]) };
    h16x2 TZ[2], TZZ[2], TR[2], TRR[2];
#pragma unroll
    for (int p = 0; p < 2; ++p) {
        h16x2 n2t = -(T[p] + T[p]);                    // -2t
        TZ[p]  = S[p] * A1[p];
        TR[p]  = S[p] * A3[p];
        TZZ[p] = n2t * (TZ[p] * A1[p]) + S[p] * A2[p]; // s*a2 - 2t*tz*a1
        TRR[p] = n2t * (TR[p] * A3[p]) + S[p] * A4[p];
    }
    const int key = (pt & 15) << 4;
    char* rb = sA + (pt << 8) + ((n * 2) ^ key);
    *(f16x4*)(rb)         = mrg(T[0], T[1]);
    *(f16x4*)(rb +  8192) = mrg(TZ[0], TZ[1]);
    *(f16x4*)(rb + 16384) = mrg(TZZ[0], TZZ[1]);
    *(f16x4*)(rb + 24576) = mrg(TR[0], TR[1]);
    *(f16x4*)(rb + 32768) = mrg(TRR[0], TRR[1]);
}

// Layer-1 variant: a1 = W1[1,:] (f32 const), a3 = W1[2,:], a2 = a4 = 0.
__device__ __forceinline__ void transform_store4_l1(
    char* sA, const f32x4 a0v, const f32x4 wz, const f32x4 wr, int pt, int n)
{
    float t[4], s[4];
#pragma unroll
    for (int r = 0; r < 4; ++r) {
        t[r] = fast_tanh(a0v[r]);
        s[r] = 1.f - t[r] * t[r];
    }
    h16x2 T[2]  = { pk(t[0], t[1]), pk(t[2], t[3]) };
    h16x2 S[2]  = { pk(s[0], s[1]), pk(s[2], s[3]) };
    h16x2 A1[2] = { pk(wz[0], wz[1]), pk(wz[2], wz[3]) };
    h16x2 A3[2] = { pk(wr[0], wr[1]), pk(wr[2], wr[3]) };
    h16x2 TZ[2], TZZ[2], TR[2], TRR[2];
#pragma unroll
    for (int p = 0; p < 2; ++p) {
        h16x2 n2t = -(T[p] + T[p]);
        TZ[p]  = S[p] * A1[p];
        TR[p]  = S[p] * A3[p];
        TZZ[p] = n2t * (TZ[p] * A1[p]);                // a2 = 0
        TRR[p] = n2t * (TR[p] * A3[p]);                // a4 = 0
    }
    const int key = (pt & 15) << 4;
    char* rb = sA + (pt << 8) + ((n * 2) ^ key);
    *(f16x4*)(rb)         = mrg(T[0], T[1]);
    *(f16x4*)(rb +  8192) = mrg(TZ[0], TZ[1]);
    *(f16x4*)(rb + 16384) = mrg(TZZ[0], TZZ[1]);
    *(f16x4*)(rb + 24576) = mrg(TR[0], TR[1]);
    *(f16x4*)(rb + 32768) = mrg(TRR[0], TRR[1]);
}

// Full 128->128 layer for 32 points by ONE wave:
// 4 neuron tiles x 5 ch x 8 ksteps = 160 MFMA (32x32x16).
// All 40 B-frags read upfront (160 VGPR, resident at (64,1) cap 512).
// No barriers: reads precede the in-place transform writes (in-order DS).
__device__ __forceinline__ void layer128w(
    char* sA, const f16* __restrict__ Wt, const float* __restrict__ b,
    int col, int hi, int key)
{
    const char* rp = sA + (col << 8);
    f16x8 Bv[5][8];
#pragma unroll
    for (int c = 0; c < 5; ++c)
#pragma unroll
        for (int ks = 0; ks < 8; ++ks)
            Bv[c][ks] = *(const f16x8*)(rp + c * 8192 + ((ks * 32 + hi * 16) ^ key));

#pragma unroll
    for (int ct0 = 0; ct0 < 4; ++ct0) {
        const int n0 = ct0 * 32;
        f32x16 acc0;
#pragma unroll
        for (int rg = 0; rg < 4; ++rg) {               // bias in C (row map)
            f32x4 bv = *(const f32x4*)&b[n0 + rg * 8 + hi * 4];
            acc0[rg * 4 + 0] = bv[0]; acc0[rg * 4 + 1] = bv[1];
            acc0[rg * 4 + 2] = bv[2]; acc0[rg * 4 + 3] = bv[3];
        }
        f32x16 acc1 = zero16(), acc2 = zero16(), acc3 = zero16(), acc4 = zero16();
#pragma unroll
        for (int ks = 0; ks < 8; ++ks) {
            f16x8 A = *(const f16x8*)&Wt[(n0 + col) * 128 + ks * 16 + hi * 8];
            acc0 = __builtin_amdgcn_mfma_f32_32x32x16_f16(A, Bv[0][ks], acc0, 0, 0, 0);
            acc1 = __builtin_amdgcn_mfma_f32_32x32x16_f16(A, Bv[1][ks], acc1, 0, 0, 0);
            acc2 = __builtin_amdgcn_mfma_f32_32x32x16_f16(A, Bv[2][ks], acc2, 0, 0, 0);
            acc3 = __builtin_amdgcn_mfma_f32_32x32x16_f16(A, Bv[3][ks], acc3, 0, 0, 0);
            acc4 = __builtin_amdgcn_mfma_f32_32x32x16_f16(A, Bv[4][ks], acc4, 0, 0, 0);
        }
#pragma unroll
        for (int rg = 0; rg < 4; ++rg) {
            const int nb = n0 + rg * 8 + hi * 4;
            f32x4 s0 = {acc0[rg*4], acc0[rg*4+1], acc0[rg*4+2], acc0[rg*4+3]};
            f32x4 s1 = {acc1[rg*4], acc1[rg*4+1], acc1[rg*4+2], acc1[rg*4+3]};
            f32x4 s2 = {acc2[rg*4], acc2[rg*4+1], acc2[rg*4+2], acc2[rg*4+3]};
            f32x4 s3 = {acc3[rg*4], acc3[rg*4+1], acc3[rg*4+2], acc3[rg*4+3]};
            f32x4 s4 = {acc4[rg*4], acc4[rg*4+1], acc4[rg*4+2], acc4[rg*4+3]};
            transform_store4(sA, s0, s1, s2, s3, s4, col, nb);
        }
    }
}

__global__ __launch_bounds__(64, 1) void pde_main(
    const float* __restrict__ X,    // N x 4
    const int*   __restrict__ fid,  // N
    const float* __restrict__ emb,  // 4 x 8
    const float* __restrict__ W1,   // 12 x 128 (rows 1,2 = tangent pre-acts)
    const float* __restrict__ b1, const float* __restrict__ b2,
    const float* __restrict__ b3,
    const f16* __restrict__ Wt1, const f16* __restrict__ Wt2,
    const f16* __restrict__ Wt3, const f16* __restrict__ Wot,
    const float* __restrict__ bot,
    float* __restrict__ partials)   // [NBLK][2]
{
    __shared__ f32x4 smem4[2560];           // 40960 B: 5ch x 32pt x 256B rows
    char* sA = (char*)smem4;

    const int lane = threadIdx.x;           // 0..63, one wave
    const int col  = lane & 31;             // point / A-row / D-col
    const int hi   = lane >> 5;             // k-half selector
    const int key  = (col & 15) << 4;
    const int p0   = blockIdx.x * PTS;

    // ---- stage layer-1 input (lanes 0..31): ch0 row = [x0..x3, emb0..7, 0 x 4].
    // Only k<16 is consumed by L1 (K=16) -> 2 swizzled b128 writes, no fill.
    float rcoord = 0.f;
    if (lane < PTS) {
        const int p = p0 + lane;
        f32x4 xr = *(const f32x4*)&X[p * 4];           // 16 B row, aligned
        rcoord = xr.z;                                 // kept for epilogue
        const float* er = &emb[fid[p] * 8];            // 32 B row, aligned
        f32x4 e0 = *(const f32x4*)er;
        f32x4 e1 = *(const f32x4*)(er + 4);
        char* rb = sA + (col << 8);
        i32x4 w0 = { bc(pk(xr.x, xr.y)), bc(pk(xr.z, xr.w)),
                     bc(pk(e0.x, e0.y)), bc(pk(e0.z, e0.w)) };
        i32x4 w1 = { bc(pk(e1.x, e1.y)), bc(pk(e1.z, e1.w)), 0, 0 };
        *(i32x4*)(rb + (0  ^ key)) = w0;
        *(i32x4*)(rb + (16 ^ key)) = w1;
    }
    // no barrier: same wave, in-order DS

    // ---- layer 1: K=16 (12 real), ch0 MFMA only; tangent chains from W1 rows ----
    {
        f16x8 Bv0 = *(const f16x8*)(sA + (col << 8) + ((hi * 16) ^ key));
#pragma unroll
        for (int ct0 = 0; ct0 < 4; ++ct0) {
            const int n0 = ct0 * 32;
            f16x8 A0 = *(const f16x8*)&Wt1[(n0 + col) * 16 + hi * 8];
            f32x16 acc0;
#pragma unroll
            for (int rg = 0; rg < 4; ++rg) {
                f32x4 bv = *(const f32x4*)&b1[n0 + rg * 8 + hi * 4];
                acc0[rg * 4 + 0] = bv[0]; acc0[rg * 4 + 1] = bv[1];
                acc0[rg * 4 + 2] = bv[2]; acc0[rg * 4 + 3] = bv[3];
            }
            acc0 = __builtin_amdgcn_mfma_f32_32x32x16_f16(A0, Bv0, acc0, 0, 0, 0);
#pragma unroll
            for (int rg = 0; rg < 4; ++rg) {
                const int nb = n0 + rg * 8 + hi * 4;
                f32x4 a0 = {acc0[rg*4], acc0[rg*4+1], acc0[rg*4+2], acc0[rg*4+3]};
                f32x4 wz = *(const f32x4*)&W1[128 + nb];   // W1 row 1 (d/dz)
                f32x4 wr = *(const f32x4*)&W1[256 + nb];   // W1 row 2 (d/dr)
                transform_store4_l1(sA, a0, wz, wr, col, nb);
            }
        }
    }

    // ---- layers 2, 3 ----
    layer128w(sA, Wt2, b2, col, hi, key);
    layer128w(sA, Wt3, b3, col, hi, key);

    // ---- output head: 32 padded out-neurons x 32 pts x 5 ch = 40 MFMA ----
    f32x16 h0, h1, h2, h3, h4;
    {
        const char* rp = sA + (col << 8);
        f16x8 Bh[5][8];
#pragma unroll
        for (int c = 0; c < 5; ++c)
#pragma unroll
            for (int ks = 0; ks < 8; ++ks)
                Bh[c][ks] = *(const f16x8*)(rp + c * 8192 + ((ks * 32 + hi * 16) ^ key));
#pragma unroll
        for (int rg = 0; rg < 4; ++rg) {               // bias in C (ch0)
            f32x4 bv = *(const f32x4*)&bot[rg * 8 + hi * 4];
            h0[rg * 4 + 0] = bv[0]; h0[rg * 4 + 1] = bv[1];
            h0[rg * 4 + 2] = bv[2]; h0[rg * 4 + 3] = bv[3];
        }
        h1 = zero16(); h2 = zero16(); h3 = zero16(); h4 = zero16();
#pragma unroll
        for (int ks = 0; ks < 8; ++ks) {
            f16x8 A = *(const f16x8*)&Wot[col * 128 + ks * 16 + hi * 8];
            h0 = __builtin_amdgcn_mfma_f32_32x32x16_f16(A, Bh[0][ks], h0, 0, 0, 0);
            h1 = __builtin_amdgcn_mfma_f32_32x32x16_f16(A, Bh[1][ks], h1, 0, 0, 0);
            h2 = __builtin_amdgcn_mfma_f32_32x32x16_f16(A, Bh[2][ks], h2, 0, 0, 0);
            h3 = __builtin_amdgcn_mfma_f32_32x32x16_f16(A, Bh[3][ks], h3, 0, 0, 0);
            h4 = __builtin_amdgcn_mfma_f32_32x32x16_f16(A, Bh[4][ks], h4, 0, 0, 0);
        }
    }
    // D: col = pt; lanes 0..31 hold neurons 0..3 in regs 0..3 (o0,o1,y0,y1 +
    // derivative channels); lanes 32..63 hold neurons 4..6 in regs 0..2.
    const int src = col + 32;
    float o4 = __shfl(h0[0], src, 64);
    float o5 = __shfl(h0[1], src, 64);
    float o6 = __shfl(h0[2], src, 64);

    // ---- residual epilogue: lanes 0..31, everything lane-local ----
    if (lane < PTS) {
        float o0   = h0[0], o1  = h0[1];
        float o0z  = h1[0], o1z = h1[1];
        float o0zz = h2[0];
        float o0r  = h3[0];
        float o0rr = h4[0];

        float sg  = __fdividef(1.f, 1.f + __expf(-o0));
        float T   = 300.f + 2000.f * sg;
        float sp  = sg * (1.f - sg);
        float spp = sp * (1.f - 2.f * sg);
        float Tz  = 2000.f * sp * o0z;
        float Tzz = 2000.f * (spp * o0z * o0z + sp * o0zz);
        float Tr  = 2000.f * sp * o0r;
        float Trr = 2000.f * (spp * o0r * o0r + sp * o0rr);

        float rs  = fmaxf(rcoord, 1e-6f);
        float lap = Trr + __fdividef(Tr, rs);
        float eres = 180.f * Tz - 0.06f * lap - 0.06f * Tzz;   // RHO*CP*VZ=180, KT=0.06

        float fv  = ((o1 > 20.f) ? o1 : __logf(1.f + __expf(o1))) * 1e-6f;
        float s1v = __fdividef(1.f, 1.f + __expf(-o1));
        float fvz = s1v * o1z * 1e-6f;

        float y0 = h0[2], y1 = h0[3], y2 = o4, y3 = o5, y4 = o6;
        float mx = fmaxf(fmaxf(fmaxf(y0, y1), fmaxf(y2, y3)), y4);
        float e0 = __expf(y0 - mx), e1 = __expf(y1 - mx), e2 = __expf(y2 - mx);
        float e3 = __expf(y3 - mx), e4 = __expf(y4 - mx);
        float inv = __fdividef(1.f, e0 + e1 + e2 + e3 + e4);
        float Yp = e3 * inv;
        float Yo = e4 * inv;

        float rT  = __fdividef(1.f, T);
        float nuc  = 1e4f * Yp * __expf(-20000.f * rT);
        float grow = 5e3f * Yp * fv * __expf(-12000.f * rT);
        float ox   = 1e5f * Yo * fv * sqrtf(T) * __expf(-16000.f * rT);
        float sres = 0.5f * fvz - nuc - grow + ox;

        float ve = eres * eres;
        float vs = sres * sres;
#pragma unroll
        for (int o = 16; o > 0; o >>= 1) {  // partners stay within lanes 0..31
            ve += __shfl_xor(ve, o, 64);
            vs += __shfl_xor(vs, o, 64);
        }
        if (lane == 0) {
            float2 w; w.x = ve; w.y = vs;
            *(float2*)&partials[2 * blockIdx.x] = w;
        }
    }
}

__global__ __launch_bounds__(1024) void pde_finalize(
    const float* __restrict__ partials, float* __restrict__ out)
{
    __shared__ double rE[1024];
    __shared__ double rS[1024];
    const int tid = threadIdx.x;
    const float2* p2 = (const float2*)partials;
    double se = 0.0, ss = 0.0;
    for (int i = tid; i < NBLK; i += 1024) {
        float2 v = p2[i];
        se += (double)v.x;
        ss += (double)v.y;
    }
    rE[tid] = se; rS[tid] = ss;
    __syncthreads();
    for (int s = 512; s > 0; s >>= 1) {
        if (tid < s) { rE[tid] += rE[tid + s]; rS[tid] += rS[tid + s]; }
        __syncthreads();
    }
    if (tid == 0) {
        const double invN = 1.0 / (double)NPTS;
        float le = (float)(rE[0] * invN);
        float ls = (float)(rS[0] * invN);
        out[0] = le;
        out[1] = ls;
        out[2] = le + ls;
    }
}

extern "C" void kernel_launch(void* const* d_in, const int* in_sizes, int n_in,
                              void* d_out, int out_size, void* d_ws, size_t ws_size,
                              hipStream_t stream)
{
    const float* X   = (const float*)d_in[0];
    const int*   fid = (const int*)  d_in[1];
    const float* W1  = (const float*)d_in[2];
    const float* b1  = (const float*)d_in[3];
    const float* W2  = (const float*)d_in[4];
    const float* b2  = (const float*)d_in[5];
    const float* W3  = (const float*)d_in[6];
    const float* b3  = (const float*)d_in[7];
    const float* Wo  = (const float*)d_in[8];
    const float* bo  = (const float*)d_in[9];
    const float* emb = (const float*)d_in[10];

    f16*   wt1      = (f16*)d_ws;                  // 128*16  f16 @ 0
    f16*   wt2      = wt1 + 128 * 16;              // 128*128 f16 @ 4096 B
    f16*   wt3      = wt2 + 128 * 128;             // 128*128 f16 @ 36864 B
    f16*   wot      = wt3 + 128 * 128;             // 32*128  f16 @ 69632 B
    float* bot      = (float*)(wot + 32 * 128);    // 32 f        @ 77824 B
    float* partials = bot + 32;                    // NBLK*2 f    @ 77952 B
    float* out      = (float*)d_out;

    prep_weights<<<128, 256, 0, stream>>>(W1, W2, W3, Wo, bo, wt1, wt2, wt3, wot, bot);
    pde_main<<<NBLK, 64, 0, stream>>>(X, fid, emb, W1, b1, b2, b3,
                                      wt1, wt2, wt3, wot, bot, partials);
    pde_finalize<<<1, 1024, 0, stream>>>(partials, out);
}

// Round 13
// 232.042 us; speedup vs baseline: 1.1269x; 1.1269x over previous
//
#include <hip/hip_runtime.h>
#include <math.h>

#define NPTS 262144
#define PTS  16
#define NBLK (NPTS / PTS)   // 16384 blocks, 64 threads (ONE wave) each

typedef _Float16 f16;
typedef f16    f16x4 __attribute__((ext_vector_type(4)));
typedef f16    f16x8 __attribute__((ext_vector_type(8)));
typedef __fp16 h16x2 __attribute__((ext_vector_type(2)));
typedef __fp16 h16x4 __attribute__((ext_vector_type(4)));
typedef float  f32x4 __attribute__((ext_vector_type(4)));
typedef int    i32x4 __attribute__((ext_vector_type(4)));

// R27 = SESSION CHAMPION (R23 restored verbatim; 173.7us kernel / 234.7us wall).
//   Final configuration after 13 experiments. Structure: single-wave blocks,
//   zero barriers (in-order wave-private DS replaces __syncthreads), layer-1
//   tangent sparsity (analytic ch1/ch3, ch2=ch4=0), bias folded into MFMA
//   C-operand, XOR-swizzled LDS (8 blocks/CU), depth-3 weight-load ring,
//   register-resident epilogue via D-layout + 3 shuffles.
//   Falsified levers (all within 174-204us): work/pt, code size, launch rate,
//   in-wave dual-stream, fused atomic finalize, LDS-read pinning, occupancy
//   8->12 streams, MFMA shape 32x32. No pipe >45%; residual stall is
//   issue/waitcnt-bound, invisible to the PMC set -- practical floor.
// MFMA 16x16x32 f16, weights as A / activations as B:
//   A: lane holds Wt[n0 + (lane&15)][k=(lane>>4)*8 + j]
//   B: lane holds act[pt=lane&15][k=(lane>>4)*8 + j]
//   D = W*act -> row = neuron = (lane>>4)*4 + reg, col = point = lane&15
// LDS: 5ch x 16pt x 128 f16 = 20480 B, AP=128 with XOR swizzle
//   byte_in_row ^= (pt&7)<<4 -> b128 B-frag reads at the wave64 minimum;
//   8 blocks/CU fit exactly (8 x 20480 = 160 KiB).

__device__ __forceinline__ h16x2 pk(float a, float b) {
    return __builtin_amdgcn_cvt_pkrtz(a, b);          // v_cvt_pkrtz_f16_f32
}
__device__ __forceinline__ f16x4 mrg(h16x2 lo, h16x2 hi) {
    h16x4 v = __builtin_shufflevector(lo, hi, 0, 1, 2, 3);
    return __builtin_bit_cast(f16x4, v);
}
__device__ __forceinline__ int bc(h16x2 v) {
    return __builtin_bit_cast(int, v);
}

__device__ __forceinline__ float fast_tanh(float z) {
    float e = __expf(2.f * z);                  // inf for large z -> t=1; 0 for very neg -> t=-1
    float r = __builtin_amdgcn_rcpf(e + 1.f);
    return __builtin_fmaf(-2.f, r, 1.f);
}

__global__ void prep_weights(const float* __restrict__ W1, const float* __restrict__ W2,
                             const float* __restrict__ W3, const float* __restrict__ Wo,
                             const float* __restrict__ bo,
                             f16* __restrict__ wt1, f16* __restrict__ wt2,
                             f16* __restrict__ wt3, f16* __restrict__ wot,
                             float* __restrict__ bot)
{
    int tid    = blockIdx.x * blockDim.x + threadIdx.x;
    int stride = gridDim.x * blockDim.x;
    for (int i = tid; i < 128 * 32; i += stride) {
        int k = i >> 7, n = i & 127;
        wt1[n * 32 + k] = (f16)((k < 12) ? W1[k * 128 + n] : 0.f);
    }
    for (int i = tid; i < 128 * 128; i += stride) {
        int k = i >> 7, n = i & 127;
        wt2[n * 128 + k] = (f16)W2[i];
        wt3[n * 128 + k] = (f16)W3[i];
    }
    for (int i = tid; i < 16 * 128; i += stride) {
        int k = i >> 4, n = i & 15;
        wot[n * 128 + k] = (f16)((n < 7) ? Wo[k * 7 + n] : 0.f);
    }
    if (tid < 16) bot[tid] = (tid < 7) ? bo[tid] : 0.f;
}

// acc[c][r] = pre-activation (bias folded into acc[0] via MFMA C-operand) of
// neuron n0q+r for point pt, channel c. Derivative chain in packed f16.
// Swizzled store: element n of row (c,pt) lives at byte c*4096 + pt*256 + ((2n)^key).
__device__ __forceinline__ void transform_store(
    char* sA, const f32x4 acc[5], int pt, int n0q)
{
    float t[4], s[4];
#pragma unroll
    for (int r = 0; r < 4; ++r) {
        t[r] = fast_tanh(acc[0][r]);
        s[r] = 1.f - t[r] * t[r];
    }
    h16x2 T[2]  = { pk(t[0], t[1]), pk(t[2], t[3]) };
    h16x2 S[2]  = { pk(s[0], s[1]), pk(s[2], s[3]) };
    h16x2 A1[2] = { pk(acc[1][0], acc[1][1]), pk(acc[1][2], acc[1][3]) };
    h16x2 A2[2] = { pk(acc[2][0], acc[2][1]), pk(acc[2][2], acc[2][3]) };
    h16x2 A3[2] = { pk(acc[3][0], acc[3][1]), pk(acc[3][2], acc[3][3]) };
    h16x2 A4[2] = { pk(acc[4][0], acc[4][1]), pk(acc[4][2], acc[4][3]) };
    h16x2 TZ[2], TZZ[2], TR[2], TRR[2];
#pragma unroll
    for (int p = 0; p < 2; ++p) {
        h16x2 n2t = -(T[p] + T[p]);                    // -2t
        TZ[p]  = S[p] * A1[p];
        TR[p]  = S[p] * A3[p];
        TZZ[p] = n2t * (TZ[p] * A1[p]) + S[p] * A2[p]; // s*a2 - 2t*tz*a1
        TRR[p] = n2t * (TR[p] * A3[p]) + S[p] * A4[p];
    }
    const int key = (pt & 7) << 4;
    char* rb = sA + (pt << 8) + (((n0q * 2)) ^ key);
    *(f16x4*)(rb)         = mrg(T[0], T[1]);
    *(f16x4*)(rb +  4096) = mrg(TZ[0], TZ[1]);
    *(f16x4*)(rb +  8192) = mrg(TZZ[0], TZZ[1]);
    *(f16x4*)(rb + 12288) = mrg(TR[0], TR[1]);
    *(f16x4*)(rb + 16384) = mrg(TRR[0], TRR[1]);
}

// Layer-1 variant: a1 = W1[1,:] (f32, per-neuron constant), a3 = W1[2,:],
// a2 = a4 = 0. Numerically identical to the one-hot MFMA path.
__device__ __forceinline__ void transform_store_l1(
    char* sA, const f32x4 acc0, const f32x4 wz, const f32x4 wr,
    int pt, int n0q)
{
    float t[4], s[4];
#pragma unroll
    for (int r = 0; r < 4; ++r) {
        t[r] = fast_tanh(acc0[r]);
        s[r] = 1.f - t[r] * t[r];
    }
    h16x2 T[2]  = { pk(t[0], t[1]), pk(t[2], t[3]) };
    h16x2 S[2]  = { pk(s[0], s[1]), pk(s[2], s[3]) };
    h16x2 A1[2] = { pk(wz[0], wz[1]), pk(wz[2], wz[3]) };
    h16x2 A3[2] = { pk(wr[0], wr[1]), pk(wr[2], wr[3]) };
    h16x2 TZ[2], TZZ[2], TR[2], TRR[2];
#pragma unroll
    for (int p = 0; p < 2; ++p) {
        h16x2 n2t = -(T[p] + T[p]);
        TZ[p]  = S[p] * A1[p];
        TR[p]  = S[p] * A3[p];
        TZZ[p] = n2t * (TZ[p] * A1[p]);                // a2 = 0
        TRR[p] = n2t * (TR[p] * A3[p]);                // a4 = 0
    }
    const int key = (pt & 7) << 4;
    char* rb = sA + (pt << 8) + (((n0q * 2)) ^ key);
    *(f16x4*)(rb)         = mrg(T[0], T[1]);
    *(f16x4*)(rb +  4096) = mrg(TZ[0], TZ[1]);
    *(f16x4*)(rb +  8192) = mrg(TZZ[0], TZZ[1]);
    *(f16x4*)(rb + 12288) = mrg(TR[0], TR[1]);
    *(f16x4*)(rb + 16384) = mrg(TRR[0], TRR[1]);
}

// Full 128->128 layer by ONE wave: 8 neuron tiles x 5 ch x 4 ksteps = 160 MFMA.
// Depth-3 software pipeline on A-frags/biases: ring slots (ct0 & 3) -- all
// indices compile-time constants after full unroll (no scratch).
// No barriers: B-frags read first (in-order DS guarantees WAR safety vs the
// in-place transform writes that follow).
__device__ __forceinline__ void layer128(
    char* sA, const f16* __restrict__ Wt, const float* __restrict__ b,
    int q, int m)
{
    const int mkey = (m & 7) << 4;
    const char* rp = sA + (m << 8);
    f16x8 Bv[5][4];
#pragma unroll
    for (int c = 0; c < 5; ++c)
#pragma unroll
        for (int kt = 0; kt < 4; ++kt)
            Bv[c][kt] = *(const f16x8*)(rp + c * 4096 + ((kt * 64 + q * 16) ^ mkey));

    const f16* wbase = &Wt[m * 128 + q * 8];
    f16x8 Ar[4][4];
    f32x4 br[4];
#pragma unroll
    for (int t = 0; t < 3; ++t) {           // prologue: tiles 0..2 in flight
        const f16* wp = wbase + (t << 11);  // tile stride = 16*128 f16
        Ar[t][0] = *(const f16x8*)(wp);
        Ar[t][1] = *(const f16x8*)(wp + 32);
        Ar[t][2] = *(const f16x8*)(wp + 64);
        Ar[t][3] = *(const f16x8*)(wp + 96);
        br[t] = *(const f32x4*)&b[t * 16 + q * 4];
    }

    const f32x4 z4 = {0.f, 0.f, 0.f, 0.f};
#pragma unroll
    for (int ct0 = 0; ct0 < 8; ++ct0) {
        if (ct0 < 5) {                      // steady-state prefetch, 3 ahead
            const int t = ct0 + 3;
            const f16* wp = wbase + (t << 11);
            Ar[t & 3][0] = *(const f16x8*)(wp);
            Ar[t & 3][1] = *(const f16x8*)(wp + 32);
            Ar[t & 3][2] = *(const f16x8*)(wp + 64);
            Ar[t & 3][3] = *(const f16x8*)(wp + 96);
            br[t & 3] = *(const f32x4*)&b[t * 16 + q * 4];
        }
        const int s = ct0 & 3;
        f32x4 acc[5];
        acc[0] = __builtin_amdgcn_mfma_f32_16x16x32_f16(Ar[s][0], Bv[0][0], br[s], 0, 0, 0);  // bias in C
#pragma unroll
        for (int c = 1; c < 5; ++c) acc[c] = __builtin_amdgcn_mfma_f32_16x16x32_f16(Ar[s][0], Bv[c][0], z4, 0, 0, 0);
#pragma unroll
        for (int c = 0; c < 5; ++c) acc[c] = __builtin_amdgcn_mfma_f32_16x16x32_f16(Ar[s][1], Bv[c][1], acc[c], 0, 0, 0);
#pragma unroll
        for (int c = 0; c < 5; ++c) acc[c] = __builtin_amdgcn_mfma_f32_16x16x32_f16(Ar[s][2], Bv[c][2], acc[c], 0, 0, 0);
#pragma unroll
        for (int c = 0; c < 5; ++c) acc[c] = __builtin_amdgcn_mfma_f32_16x16x32_f16(Ar[s][3], Bv[c][3], acc[c], 0, 0, 0);

        transform_store(sA, acc, m, ct0 * 16 + q * 4);
    }
}

__global__ __launch_bounds__(64, 2) void pde_main(
    const float* __restrict__ X,    // N x 4
    const int*   __restrict__ fid,  // N
    const float* __restrict__ emb,  // 4 x 8
    const float* __restrict__ W1,   // 12 x 128 (rows 1,2 = tangent pre-acts)
    const float* __restrict__ b1, const float* __restrict__ b2,
    const float* __restrict__ b3,
    const f16* __restrict__ Wt1, const f16* __restrict__ Wt2,
    const f16* __restrict__ Wt3, const f16* __restrict__ Wot,
    const float* __restrict__ bot,
    float* __restrict__ partials)   // [NBLK][2]
{
    __shared__ f32x4 smem4[1280];           // 20480 B: 5ch x 16pt x 256B rows
    char* sA = (char*)smem4;

    const int lane = threadIdx.x;           // 0..63, one wave
    const int q    = lane >> 4;             // quad 0..3
    const int m    = lane & 15;             // point / A-row
    const int p0   = blockIdx.x * PTS;

    // ---- stage layer-1 input (lanes 0..15): ch0 = [x0..x3, emb0..7, 0 x 20].
    // 4 x b128 swizzled stores (16B chunks (0,16,32,48)^key stay 16B-aligned).
    float rcoord = 0.f;
    if (lane < PTS) {
        const int p = lane;
        f32x4 xr = *(const f32x4*)&X[(p0 + p) * 4];        // 16 B row, aligned
        rcoord = xr.z;                                     // kept for epilogue
        const float* er = &emb[fid[p0 + p] * 8];           // 32 B row, aligned
        f32x4 e0 = *(const f32x4*)er;
        f32x4 e1 = *(const f32x4*)(er + 4);
        const int key = (p & 7) << 4;
        char* rb = sA + (p << 8);
        i32x4 w0 = { bc(pk(xr.x, xr.y)), bc(pk(xr.z, xr.w)),
                     bc(pk(e0.x, e0.y)), bc(pk(e0.z, e0.w)) };
        i32x4 w1 = { bc(pk(e1.x, e1.y)), bc(pk(e1.z, e1.w)), 0, 0 };
        const i32x4 z16 = {0, 0, 0, 0};
        *(i32x4*)(rb + (0  ^ key)) = w0;
        *(i32x4*)(rb + (16 ^ key)) = w1;
        *(i32x4*)(rb + (32 ^ key)) = z16;
        *(i32x4*)(rb + (48 ^ key)) = z16;
    }
    // no barrier: same wave, in-order DS

    // ---- layer 1: K=32 (12 real), ch0 MFMA only; tangent chains from W1 rows ----
    {
        const int mkey = (m & 7) << 4;
        f16x8 Bv0 = *(const f16x8*)(sA + (m << 8) + ((q * 16) ^ mkey));
#pragma unroll
        for (int ct0 = 0; ct0 < 8; ++ct0) {
            const int n0 = ct0 * 16;
            f16x8 A0 = *(const f16x8*)&Wt1[(n0 + m) * 32 + q * 8];
            f32x4 bb = *(const f32x4*)&b1[n0 + q * 4];
            f32x4 acc0 = __builtin_amdgcn_mfma_f32_16x16x32_f16(A0, Bv0, bb, 0, 0, 0);
            f32x4 wz = *(const f32x4*)&W1[128 + n0 + q * 4];   // W1 row 1 (d/dz)
            f32x4 wr = *(const f32x4*)&W1[256 + n0 + q * 4];   // W1 row 2 (d/dr)
            transform_store_l1(sA, acc0, wz, wr, m, n0 + q * 4);
        }
    }

    // ---- layers 2, 3 ----
    layer128(sA, Wt2, b2, q, m);
    layer128(sA, Wt3, b3, q, m);

    // ---- output head: whole wave, 16 out-neurons x 16 pts x 5 ch = 20 MFMA ----
    f32x4 acc[5];
    {
        const int mkey = (m & 7) << 4;
        const char* rp = sA + (m << 8);
        f16x8 Bh[5][4];
#pragma unroll
        for (int c = 0; c < 5; ++c)
#pragma unroll
            for (int kt = 0; kt < 4; ++kt)
                Bh[c][kt] = *(const f16x8*)(rp + c * 4096 + ((kt * 64 + q * 16) ^ mkey));
        f32x4 c0i = *(const f32x4*)&bot[q * 4];       // bias folds into ch0 C
        const f16* wp = &Wot[m * 128 + q * 8];
        f16x8 A0 = *(const f16x8*)(wp);
        f16x8 A1 = *(const f16x8*)(wp + 32);
        f16x8 A2 = *(const f16x8*)(wp + 64);
        f16x8 A3 = *(const f16x8*)(wp + 96);
        const f32x4 z4 = {0.f, 0.f, 0.f, 0.f};
        acc[0] = __builtin_amdgcn_mfma_f32_16x16x32_f16(A0, Bh[0][0], c0i, 0, 0, 0);
#pragma unroll
        for (int c = 1; c < 5; ++c) acc[c] = __builtin_amdgcn_mfma_f32_16x16x32_f16(A0, Bh[c][0], z4, 0, 0, 0);
#pragma unroll
        for (int c = 0; c < 5; ++c) acc[c] = __builtin_amdgcn_mfma_f32_16x16x32_f16(A1, Bh[c][1], acc[c], 0, 0, 0);
#pragma unroll
        for (int c = 0; c < 5; ++c) acc[c] = __builtin_amdgcn_mfma_f32_16x16x32_f16(A2, Bh[c][2], acc[c], 0, 0, 0);
#pragma unroll
        for (int c = 0; c < 5; ++c) acc[c] = __builtin_amdgcn_mfma_f32_16x16x32_f16(A3, Bh[c][3], acc[c], 0, 0, 0);
    }
    // D layout: lane = pt (col) for lanes 0..15 (neurons 0..3 in regs);
    // lanes 16..31 hold neurons 4..7. Fetch o4..o6 (softmax y2..y4) by shuffle.
    const int src = (lane & 15) + 16;
    float o4 = __shfl(acc[0][0], src, 64);
    float o5 = __shfl(acc[0][1], src, 64);
    float o6 = __shfl(acc[0][2], src, 64);

    // ---- residual epilogue: lanes 0..15, everything lane-local ----
    if (lane < PTS) {
        float o0   = acc[0][0], o1  = acc[0][1];
        float o0z  = acc[1][0], o1z = acc[1][1];
        float o0zz = acc[2][0];
        float o0r  = acc[3][0];
        float o0rr = acc[4][0];

        float sg  = __fdividef(1.f, 1.f + __expf(-o0));
        float T   = 300.f + 2000.f * sg;
        float sp  = sg * (1.f - sg);
        float spp = sp * (1.f - 2.f * sg);
        float Tz  = 2000.f * sp * o0z;
        float Tzz = 2000.f * (spp * o0z * o0z + sp * o0zz);
        float Tr  = 2000.f * sp * o0r;
        float Trr = 2000.f * (spp * o0r * o0r + sp * o0rr);

        float rs  = fmaxf(rcoord, 1e-6f);
        float lap = Trr + __fdividef(Tr, rs);
        float eres = 180.f * Tz - 0.06f * lap - 0.06f * Tzz;   // RHO*CP*VZ=180, KT=0.06

        float fv  = ((o1 > 20.f) ? o1 : __logf(1.f + __expf(o1))) * 1e-6f;
        float s1  = __fdividef(1.f, 1.f + __expf(-o1));
        float fvz = s1 * o1z * 1e-6f;

        float y0 = acc[0][2], y1 = acc[0][3], y2 = o4, y3 = o5, y4 = o6;
        float mx = fmaxf(fmaxf(fmaxf(y0, y1), fmaxf(y2, y3)), y4);
        float e0 = __expf(y0 - mx), e1 = __expf(y1 - mx), e2 = __expf(y2 - mx);
        float e3 = __expf(y3 - mx), e4 = __expf(y4 - mx);
        float inv = __fdividef(1.f, e0 + e1 + e2 + e3 + e4);
        float Yp = e3 * inv;
        float Yo = e4 * inv;

        float rT  = __fdividef(1.f, T);
        float nuc  = 1e4f * Yp * __expf(-20000.f * rT);
        float grow = 5e3f * Yp * fv * __expf(-12000.f * rT);
        float ox   = 1e5f * Yo * fv * sqrtf(T) * __expf(-16000.f * rT);
        float sres = 0.5f * fvz - nuc - grow + ox;

        float ve = eres * eres;
        float vs = sres * sres;
#pragma unroll
        for (int o = 8; o > 0; o >>= 1) {   // partners stay within lanes 0..15
            ve += __shfl_xor(ve, o, 64);
            vs += __shfl_xor(vs, o, 64);
        }
        if (lane == 0) {
            float2 w; w.x = ve; w.y = vs;
            *(float2*)&partials[2 * blockIdx.x] = w;
        }
    }
}

__global__ __launch_bounds__(1024) void pde_finalize(
    const float* __restrict__ partials, float* __restrict__ out)
{
    __shared__ double rE[1024];
    __shared__ double rS[1024];
    const int tid = threadIdx.x;
    const float2* p2 = (const float2*)partials;
    double se = 0.0, ss = 0.0;
    for (int i = tid; i < NBLK; i += 1024) {
        float2 v = p2[i];
        se += (double)v.x;
        ss += (double)v.y;
    }
    rE[tid] = se; rS[tid] = ss;
    __syncthreads();
    for (int s = 512; s > 0; s >>= 1) {
        if (tid < s) { rE[tid] += rE[tid + s]; rS[tid] += rS[tid + s]; }
        __syncthreads();
    }
    if (tid == 0) {
        const double invN = 1.0 / (double)NPTS;
        float le = (float)(rE[0] * invN);
        float ls = (float)(rS[0] * invN);
        out[0] = le;
        out[1] = ls;
        out[2] = le + ls;
    }
}

extern "C" void kernel_launch(void* const* d_in, const int* in_sizes, int n_in,
                              void* d_out, int out_size, void* d_ws, size_t ws_size,
                              hipStream_t stream)
{
    const float* X   = (const float*)d_in[0];
    const int*   fid = (const int*)  d_in[1];
    const float* W1  = (const float*)d_in[2];
    const float* b1  = (const float*)d_in[3];
    const float* W2  = (const float*)d_in[4];
    const float* b2  = (const float*)d_in[5];
    const float* W3  = (const float*)d_in[6];
    const float* b3  = (const float*)d_in[7];
    const float* Wo  = (const float*)d_in[8];
    const float* bo  = (const float*)d_in[9];
    const float* emb = (const float*)d_in[10];

    f16*   wt1      = (f16*)d_ws;                  // 128*32   @ 0
    f16*   wt2      = wt1 + 128 * 32;              // 128*128  @ 8192 B
    f16*   wt3      = wt2 + 128 * 128;             // 128*128  @ 40960 B
    f16*   wot      = wt3 + 128 * 128;             // 16*128   @ 73728 B
    float* bot      = (float*)(wot + 16 * 128);    // 16 f     @ 77824 B
    float* partials = bot + 16;                    // NBLK*2 f @ 77888 B
    float* out      = (float*)d_out;

    prep_weights<<<128, 256, 0, stream>>>(W1, W2, W3, Wo, bo, wt1, wt2, wt3, wot, bot);
    pde_main<<<NBLK, 64, 0, stream>>>(X, fid, emb, W1, b1, b2, b3,
                                      wt1, wt2, wt3, wot, bot, partials);
    pde_finalize<<<1, 1024, 0, stream>>>(partials, out);
}